// Round 7
// baseline (224.403 us; speedup 1.0000x reference)
//
#include <hip/hip_runtime.h>

// Problem constants: b=1, m=128, n=256 (positions), c=22 classes
#define NC    22
#define NROW  (NC*NC)        // 484 floats per (i,j) coupling block
#define NJ    256
#define NI    256
#define NM    128
#define JG    8              // j's per superstep
#define NQJ   4              // j-quarters (blockIdx.y) -> 1024 blocks, 4/CU
#define JQ    (NJ/NQJ)       // 64 j's per block
#define SS    (JQ/JG)        // 8 supersteps
#define ROWDW 16             // dwords per (j,c) row: 32 bf16 (d padded 22->32)
#define JROW  (NC*ROWDW)     // 352 dwords per j
#define TILEDW (JG*JROW)     // 2816 dwords per buffer (11264 B)
#define F4PS  (JG*NROW/4)    // 968 float4 staged per superstep
#define AJSTR (4*NM*4)       // afrag dwords per j: 4 quads * 128 m * 4 dw

typedef __attribute__((ext_vector_type(8))) short short8;  // bf16x8 A/B frag
typedef __attribute__((ext_vector_type(4))) float f32x4;   // fp32x4 C/D frag
union frag_u { uint4 v; uint32_t u[4]; short8 s; };

// One-hot A-fragment table: afrag[j][q][m] = 4 dwords (8 bf16), the K-quad-q
// slice of the one-hot row for (m,j). Depends only on variant -> built once,
// reused by all 256 i-blocks (2 MB, L2-resident).
__global__ __launch_bounds__(128) void build_afrag(
    const int* __restrict__ variant,  // [128,256]
    uint32_t*  __restrict__ afrag)    // [256,4,128,4] dwords
{
    const int j = blockIdx.x;
    const int m = threadIdx.x;
    const int v = variant[m * NJ + j];
    const uint32_t pat = 0x3F80u << ((v & 1) << 4);  // 1.0bf16 in (v&1) half
    #pragma unroll
    for (int q = 0; q < 4; ++q) {
        uint4 w;
        w.x = ((v >> 1) == q * 4 + 0) ? pat : 0u;
        w.y = ((v >> 1) == q * 4 + 1) ? pat : 0u;
        w.z = ((v >> 1) == q * 4 + 2) ? pat : 0u;
        w.w = ((v >> 1) == q * 4 + 3) ? pat : 0u;
        ((uint4*)afrag)[(j * 4 + q) * NM + m] = w;   // lanes m -> contiguous
    }
}

// part[jq][i][m][c] = sum_{j in quarter} eij[i,j,c,v[m,j]] * mask_vec[v[m,j]]
// MFMA: A = one-hot (from global afrag table, off the LDS pipe), B = bf16 em
// tile in LDS (native d-order -> ds_read_b128, no transpose).
// LDS budget/wave-ss: 8 b32 writes + 16 b128 reads ~ 240 cyc -> 12.8 us/CU,
// below the ~21 us HBM floor. R6 spent 357 cyc (vtab reads/writes + VALU
// A-build); that and staging VALU are what this round removes.
__global__ __launch_bounds__(256) void potts_mfma(
    const float*    __restrict__ eij,      // [256,256,22,22]
    const float*    __restrict__ mask_vec, // [22]
    const uint32_t* __restrict__ afrag,    // [256,4,128,4]
    float*          __restrict__ part)     // [4,256,128,22] workspace
{
    const int i    = blockIdx.x;
    const int jq   = blockIdx.y;
    const int tid  = threadIdx.x;
    const int lane = tid & 63;
    const int wv   = tid >> 6;           // wave 0..3
    const int q    = lane >> 4;          // k-quad / row-quad
    const int nl   = lane & 15;          // fragment row/col index

    __shared__ uint32_t tile[2][TILEDW]; // bf16 em tiles, 22528 B total

    // Zero the d-pad (w=11..15 of every (j,c) row) once per buffer. A is zero
    // at d>=22, but junk here could be NaN (NaN*0=NaN) -> must be 0.
    for (int p = tid; p < 2 * JG * NC * 5; p += 256) {
        const int b  = p / (JG * NC * 5), r = p % (JG * NC * 5);
        const int jl = r / (NC * 5),     r2 = r % (NC * 5);
        tile[b][jl * JROW + (r2 / 5) * ROWDW + 11 + r2 % 5] = 0;
    }

    // Staging decomposition: float4 f4 = r*256+tid covers 968 float4 = 8 j of
    // 484 floats; 121 float4/j (no straddle); each float2 half sits inside one
    // 22-float c-row. Mask folded at stage time.
    int   l0[4], l1[4];
    float mk[4][4];
    bool  act[4];
    #pragma unroll
    for (int r = 0; r < 4; ++r) {
        const int f4 = r * 256 + tid;
        act[r] = (f4 < F4PS);
        const int fc = act[r] ? f4 : 0;
        const int jl = fc / 121, r4 = fc % 121;
        const int f2a = 2 * r4, f2b = f2a + 1;
        const int ca = f2a / 11, wa = f2a % 11;
        const int cb = f2b / 11, wb = f2b % 11;
        l0[r] = jl * JROW + ca * ROWDW + wa;
        l1[r] = jl * JROW + cb * ROWDW + wb;
        mk[r][0] = mask_vec[2 * wa];  mk[r][1] = mask_vec[2 * wa + 1];
        mk[r][2] = mask_vec[2 * wb];  mk[r][3] = mask_vec[2 * wb + 1];
    }

    const float4* gsrc = (const float4*)eij + (size_t)(i * NJ + jq * JQ) * 121;

    // Wave-constant addresses. nt frag 1 covers c=16..31; lanes c>=22 clamp to
    // row 0 (real data, never NaN); their D columns are discarded.
    const int c1   = 16 + nl;
    const int off0 = nl * ROWDW + q * 4;
    const int off1 = (c1 < NC ? c1 : 0) * ROWDW + q * 4;
    const int m0a  = wv * 16;            // m-tiles: wv*16 and wv*16+64
    // Per-lane afrag pointer (dwords): [(j*4+q)*128 + m]*4
    const uint32_t* abase = afrag + (size_t)(jq * JQ) * AJSTR
                          + (q * NM + m0a + nl) * 4;

    f32x4 acc_a0 = {0.f,0.f,0.f,0.f}, acc_a1 = {0.f,0.f,0.f,0.f};
    f32x4 acc_b0 = {0.f,0.f,0.f,0.f}, acc_b1 = {0.f,0.f,0.f,0.f};

    // Prefetch superstep 0
    float4 pf[4];
    #pragma unroll
    for (int r = 0; r < 4; ++r)
        if (act[r]) pf[r] = gsrc[r * 256 + tid];

    for (int s = 0; s < SS; ++s) {
        uint32_t* buf = tile[s & 1];

        // Stage em as bf16: round via +0x8000 on the bit pattern, then pack
        // two high halves with one v_perm_b32 (sel 0x07060302: lo16=src1.hi,
        // hi16=src0.hi). 10 VALU per float4 vs ~20 for rne+shift+or.
        #pragma unroll
        for (int r = 0; r < 4; ++r) {
            if (act[r]) {
                const float4 v = pf[r];
                const uint32_t ax = __float_as_uint(v.x * mk[r][0]) + 0x8000u;
                const uint32_t ay = __float_as_uint(v.y * mk[r][1]) + 0x8000u;
                const uint32_t az = __float_as_uint(v.z * mk[r][2]) + 0x8000u;
                const uint32_t aw = __float_as_uint(v.w * mk[r][3]) + 0x8000u;
                buf[l0[r]] = __builtin_amdgcn_perm(ay, ax, 0x07060302u);
                buf[l1[r]] = __builtin_amdgcn_perm(aw, az, 0x07060302u);
            }
        }
        __syncthreads();
        // One barrier per superstep suffices with double buffering (R1/R6):
        // the next write to this buffer happens one barrier later, after all
        // reads from superstep s-1 retired in program order.

        // Prefetch next superstep
        if (s + 1 < SS) {
            const float4* gn = gsrc + (size_t)(s + 1) * F4PS;
            #pragma unroll
            for (int r = 0; r < 4; ++r)
                if (act[r]) pf[r] = gn[r * 256 + tid];
        }

        const uint32_t* ass = abase + (size_t)s * JG * AJSTR;

        // Per wave per j: 2 afrag dwordx4 (L2) + 2 B-frag ds_read_b128
        // (conflict-free: 64 lanes -> 64 distinct aligned 16B chunks) + 4 MFMA
        #pragma unroll
        for (int jl = 0; jl < JG; ++jl) {
            const uint32_t* jrow = buf + jl * JROW;
            const short8 bf0 = *(const short8*)(jrow + off0);
            const short8 bf1 = *(const short8*)(jrow + off1);

            frag_u fa, fb;
            fa.v = *(const uint4*)(ass + jl * AJSTR);
            fb.v = *(const uint4*)(ass + jl * AJSTR + 64 * 4);  // m-set +64

            acc_a0 = __builtin_amdgcn_mfma_f32_16x16x32_bf16(fa.s, bf0, acc_a0, 0, 0, 0);
            acc_a1 = __builtin_amdgcn_mfma_f32_16x16x32_bf16(fa.s, bf1, acc_a1, 0, 0, 0);
            acc_b0 = __builtin_amdgcn_mfma_f32_16x16x32_bf16(fb.s, bf0, acc_b0, 0, 0, 0);
            acc_b1 = __builtin_amdgcn_mfma_f32_16x16x32_bf16(fb.s, bf1, acc_b1, 0, 0, 0);
        }
    }

    // Epilogue: C/D layout col=lane&15, row=(lane>>4)*4+reg (m89-verified).
    float* pbase = part + ((size_t)jq * NI + i) * NM * NC;
    #pragma unroll
    for (int t = 0; t < 4; ++t) {
        const int ra = m0a + q * 4 + t, rb = ra + 64;
        pbase[ra * NC + nl] = acc_a0[t];
        pbase[rb * NC + nl] = acc_b0[t];
        if (c1 < NC) {
            pbase[ra * NC + c1] = acc_a1[t];
            pbase[rb * NC + c1] = acc_b1[t];
        }
    }
}

// motifs[m,i,c] = ei[i,c] + sum_jq part[jq,i,m,c];  logits[m,i]=motifs[m,i,v[m,i]]
// Block = m, thread = i: motifs writes are contiguous 88 B/thread -> 5.6 KB
// per wave (R6's layout scattered lanes at 22.5 KB stride).
__global__ __launch_bounds__(256) void potts_reduce(
    const float* __restrict__ part,      // [4,256,128,22]
    const int*   __restrict__ variant,   // [128,256]
    const float* __restrict__ ei,        // [256,22]
    float*       __restrict__ out_motifs,// [128,256,22]
    float*       __restrict__ out_logits)// [128,256]
{
    const int m = blockIdx.x;
    const int i = threadIdx.x;

    const float* p0 = part + (((size_t)0 * NI + i) * NM + m) * NC;
    const float* p1 = part + (((size_t)1 * NI + i) * NM + m) * NC;
    const float* p2 = part + (((size_t)2 * NI + i) * NM + m) * NC;
    const float* p3 = part + (((size_t)3 * NI + i) * NM + m) * NC;
    const float* eirow = ei + i * NC;
    float* mout = out_motifs + ((size_t)m * NI + i) * NC;
    const int vi = variant[m * NJ + i];

    float logit = 0.f;
    #pragma unroll
    for (int k = 0; k < NC; ++k) {
        const float v = p0[k] + p1[k] + p2[k] + p3[k] + eirow[k];
        mout[k] = v;
        if (k == vi) logit = v;
    }
    out_logits[m * NI + i] = logit;
}

// variant_logit[m] = sigma * sum_i (logits[m,i]-logits[0,i]) * vm[m,i]*vm[0,i]
__global__ __launch_bounds__(64) void potts_pool(
    const float* __restrict__ logits,  // [128,256]
    const float* __restrict__ vmask,   // [128,256]
    const float* __restrict__ sigma,   // [1]
    float*       __restrict__ out_vl)  // [128]
{
    const int m    = blockIdx.x;
    const int lane = threadIdx.x;
    float s = 0.f;
    #pragma unroll
    for (int qq = 0; qq < 4; ++qq) {
        const int i = lane + 64 * qq;
        const float vl = logits[m * NI + i] - logits[i];
        s += vl * vmask[m * NI + i] * vmask[i];
    }
    #pragma unroll
    for (int off = 32; off > 0; off >>= 1)
        s += __shfl_down(s, off, 64);
    if (lane == 0) out_vl[m] = sigma[0] * s;
}

extern "C" void kernel_launch(void* const* d_in, const int* in_sizes, int n_in,
                              void* d_out, int out_size, void* d_ws, size_t ws_size,
                              hipStream_t stream) {
    const int*   variant  = (const int*)  d_in[0];  // [1,128,256] int32
    const float* vmask    = (const float*)d_in[1];  // [1,128,256]
    const float* eij      = (const float*)d_in[2];  // [1,256,256,22,22]
    const float* ei       = (const float*)d_in[3];  // [1,256,22]
    const float* mask_vec = (const float*)d_in[4];  // [22]
    const float* sigma    = (const float*)d_in[5];  // [1]

    float* out        = (float*)d_out;
    float* out_motifs = out;                        // 128*256*22
    float* out_logits = out_motifs + NM * NI * NC;  // 128*256
    float* out_vl     = out_logits + NM * NI;       // 128

    float*    part   = (float*)d_ws;                // 11.5 MB
    uint32_t* afrag  = (uint32_t*)(part + 4 * NI * NM * NC);  // +2 MB

    build_afrag<<<NJ, NM, 0, stream>>>(variant, afrag);
    dim3 gridA(NI, NQJ);
    potts_mfma<<<gridA, 256, 0, stream>>>(eij, mask_vec, afrag, part);
    potts_reduce<<<NM, NI, 0, stream>>>(part, variant, ei,
                                        out_motifs, out_logits);
    potts_pool<<<NM, 64, 0, stream>>>(out_logits, vmask, sigma, out_vl);
}